// Round 17
// baseline (463.165 us; speedup 1.0000x reference)
//
#include <hip/hip_runtime.h>
#include <cstdint>

#define N_NODES 200000
#define N_EDGES 3200000
#define F_IN 128
#define CH 32
#define N_GRAPHS 1024
#define N_LABELS 17

#define BROWS 512                 // rows per bucket
#define NBUCK ((N_NODES + BROWS - 1) / BROWS)   // 391
#define CAP 10240                 // record capacity per bucket (mean 8192, sd ~90)
#define EPB 8192                  // edges per workgroup in pass A

typedef unsigned int uint32;
typedef unsigned short u16;

#define TSCALE 16.f               // int8 t-table fixed-point scale (abs err 1/32)
#define TSTRIDE 130               // LDS tile row stride in shorts (260B: odd*4 -> bank spread)

__device__ __forceinline__ u16 f2bf(float f) {
  unsigned int u = __float_as_uint(f);
  u = (u + 0x7FFFu + ((u >> 16) & 1u)) >> 16;  // round-to-nearest-even
  return (u16)u;
}
__device__ __forceinline__ float bf2f(u16 h) {
  return __uint_as_float(((unsigned int)h) << 16);
}
__device__ __forceinline__ signed char f2q8(float f) {
  float qf = fmaxf(-127.f, fminf(127.f, rintf(f * TSCALE)));
  return (signed char)(int)qf;
}

// =======================================================================
// Pass A: bucket edges into per-bucket record regions (packed 8B records)
// record = ((rl<<18 | col) << 32) | float_bits(val)
// =======================================================================

__global__ __launch_bounds__(256) void k_passA(const int* __restrict__ arow,
                                               const int* __restrict__ acol,
                                               const float* __restrict__ aval,
                                               int* __restrict__ bucketCur,
                                               unsigned long long* __restrict__ records) {
  __shared__ int cnt[NBUCK];
  __shared__ int base[NBUCK];
  int t = threadIdx.x;
  for (int i = t; i < NBUCK; i += 256) cnt[i] = 0;
  __syncthreads();
  int e0 = blockIdx.x * EPB;
  int e1 = e0 + EPB; if (e1 > N_EDGES) e1 = N_EDGES;
  for (int e = e0 + t; e < e1; e += 256) atomicAdd(&cnt[arow[e] >> 9], 1);
  __syncthreads();
  for (int i = t; i < NBUCK; i += 256) {
    int n = cnt[i];
    base[i] = n ? atomicAdd(&bucketCur[i], n) : 0;
    cnt[i] = 0;  // reuse as local cursor
  }
  __syncthreads();
  for (int e = e0 + t; e < e1; e += 256) {
    int r = arow[e];
    int b = r >> 9;
    int p = atomicAdd(&cnt[b], 1) + base[b];
    if (p < CAP) {
      unsigned int hi = ((unsigned int)(r & 511) << 18) | (unsigned int)acol[e];
      unsigned long long rec = ((unsigned long long)hi << 32) |
                               (unsigned int)__float_as_int(aval[e]);
      records[(size_t)b * CAP + p] = rec;
    }
  }
}

// =======================================================================
// Pass B: one WG per bucket -> exact compact CSR
// edge record: 4 bytes = (col:18 << 14) | q14(val); val = q * (1/16383)
// =======================================================================

__global__ __launch_bounds__(512) void k_passB(const int* __restrict__ bucketCur,
                                               const unsigned long long* __restrict__ records,
                                               int2* __restrict__ rowinfo,
                                               uint32* __restrict__ edges) {
  __shared__ int cnt[BROWS];
  __shared__ int sc[BROWS];
  __shared__ int cur[BROWS];
  int b = blockIdx.x;
  int t = threadIdx.x;
  int nrec = bucketCur[b]; if (nrec > CAP) nrec = CAP;
  const unsigned long long* rp = records + (size_t)b * CAP;
  cnt[t] = 0;
  __syncthreads();
  for (int i = t; i < nrec; i += 512) {
    unsigned int hi = (unsigned int)(rp[i] >> 32);
    atomicAdd(&cnt[hi >> 18], 1);
  }
  __syncthreads();
  sc[t] = cnt[t];
  __syncthreads();
  for (int d = 1; d < BROWS; d <<= 1) {
    int v = (t >= d) ? sc[t - d] : 0;
    __syncthreads();
    sc[t] += v;
    __syncthreads();
  }
  int pre = sc[t] - cnt[t];  // exclusive prefix
  cur[t] = pre;
  int r = b * BROWS + t;
  if (r < N_NODES) rowinfo[r] = make_int2(b * CAP + pre, cnt[t]);
  __syncthreads();
  for (int i = t; i < nrec; i += 512) {
    unsigned long long rec = rp[i];
    unsigned int hi = (unsigned int)(rec >> 32);
    int rl = hi >> 18;
    unsigned int col = hi & 0x3FFFFu;
    float val = __int_as_float((int)(unsigned int)rec);
    int q = (int)fmaf(val, 16383.f, 0.5f);
    q = q < 0 ? 0 : (q > 16383 ? 16383 : q);
    int p = atomicAdd(&cur[rl], 1);
    edges[(size_t)b * CAP + p] = (col << 14) | (unsigned int)q;
  }
}

// =======================================================================
// x transpose: x [node][128] fp32 -> xT [kp][node] u32 (bf16 pair 2kp,2kp+1)
// BOTH sides coalesced (r10 bug fixed: write phase maps consecutive lanes
// to consecutive NODES, 256B/instruction). LDS row stride 130 shorts ->
// read banks (t+kp)%32 (2-way, free), write banks 2-way per row pair.
// 65KB LDS -> 2 WGs/CU; streaming, ~153MB total.
// =======================================================================

__global__ __launch_bounds__(256) void k_xpose(const float* __restrict__ x,
                                               uint32* __restrict__ xT) {
  __shared__ u16 tile[256 * TSTRIDE];   // 66560 B
  int t = threadIdx.x;
  size_t wgNode = (size_t)blockIdx.x * 256;
  const float4* x4 = (const float4*)x;
  // ---- read phase: 256 rows x 32 float4, fully coalesced ----
#pragma unroll
  for (int j = 0; j < 32; j++) {
    int idx = t + 256 * j;          // float4 slot in this 256x128 slab
    int row = idx >> 5;             // 0..255
    int sub = idx & 31;             // float4 within row
    if (wgNode + (size_t)row < N_NODES) {
      float4 v = x4[wgNode * 32 + idx];
      uint32 lo = (uint32)f2bf(v.x) | ((uint32)f2bf(v.y) << 16);
      uint32 hi = (uint32)f2bf(v.z) | ((uint32)f2bf(v.w) << 16);
      uint32* dst = (uint32*)&tile[row * TSTRIDE + sub * 4];
      dst[0] = lo;
      dst[1] = hi;
    }
  }
  __syncthreads();
  // ---- write phase: per kp, 256 consecutive nodes' u32 (coalesced) ----
  size_t node = wgNode + t;
  if (node >= N_NODES) return;
#pragma unroll
  for (int kp = 0; kp < 64; kp++) {
    uint32 v = *(const uint32*)&tile[t * TSTRIDE + kp * 2];
    xT[(size_t)kp * N_NODES + node] = v;
  }
}

// =======================================================================
// dense layer 1 on transposed x: t = x@W1 (int8 out), s = x@W2 (bf16 out)
// Load-use loop (r9-proven pipelining pattern — NO staging arrays, r10/r14
// lesson). Per load instruction the wave touches 4 lines (256B coalesced)
// instead of 64 -> the per-CU miss queue stops being the limiter.
// Weights stay on the SGPR/scalar path (kp loop-uniform).
// =======================================================================

__global__ __launch_bounds__(256) void k_dense1(const uint32* __restrict__ xT,
                                                const float* __restrict__ W1,
                                                const float* __restrict__ W2,
                                                signed char* __restrict__ tout,
                                                u16* __restrict__ sout) {
  int node = blockIdx.x * blockDim.x + threadIdx.x;
  if (node >= N_NODES) return;
  float acc1[CH], acc2[CH];
#pragma unroll
  for (int c = 0; c < CH; c++) { acc1[c] = 0.f; acc2[c] = 0.f; }
#pragma unroll 8
  for (int kp = 0; kp < 64; kp++) {
    uint32 wv = xT[(size_t)kp * N_NODES + node];
    float xlo = bf2f((u16)(wv & 0xffffu));
    float xhi = bf2f((u16)(wv >> 16));
    const float* w1r = W1 + (size_t)(2 * kp) * CH;
    const float* w2r = W2 + (size_t)(2 * kp) * CH;
#pragma unroll
    for (int c = 0; c < CH; c++) {
      acc1[c] = fmaf(xlo, w1r[c], acc1[c]);
      acc2[c] = fmaf(xlo, w2r[c], acc2[c]);
    }
#pragma unroll
    for (int c = 0; c < CH; c++) {
      acc1[c] = fmaf(xhi, w1r[CH + c], acc1[c]);
      acc2[c] = fmaf(xhi, w2r[CH + c], acc2[c]);
    }
  }
  uint32* tp = (uint32*)(tout + (size_t)node * CH);
#pragma unroll
  for (int c = 0; c < CH; c += 4) {
    uint32 p = ((uint32)(unsigned char)f2q8(acc1[c])) |
               ((uint32)(unsigned char)f2q8(acc1[c + 1]) << 8) |
               ((uint32)(unsigned char)f2q8(acc1[c + 2]) << 16) |
               ((uint32)(unsigned char)f2q8(acc1[c + 3]) << 24);
    tp[c >> 2] = p;
  }
  uint32* sp = (uint32*)(sout + (size_t)node * CH);
#pragma unroll
  for (int c = 0; c < CH; c += 2) {
    sp[c >> 1] = (uint32)f2bf(acc2[c]) | ((uint32)f2bf(acc2[c + 1]) << 16);
  }
}

// =======================================================================
// Fused: agg = SpMM(t_int8) ; h = relu(agg + s + b) ; [t',s'] = h @ [W1n,W2n]
// Edge words: one coalesced load per 16 + in-register shfl broadcast.
// =======================================================================

template <int MODE>
__global__ __launch_bounds__(256) void k_gcs(const int2* __restrict__ rowinfo,
                                             const uint32* __restrict__ edges,
                                             const signed char* __restrict__ tin,
                                             u16* __restrict__ sio,
                                             const float* __restrict__ bias,
                                             const float* __restrict__ W1n,
                                             const float* __restrict__ W2n,
                                             signed char* __restrict__ tout,
                                             float* __restrict__ hout) {
  int gid = blockIdx.x * blockDim.x + threadIdx.x;
  int node = gid >> 5;
  int c = gid & 31;
  if (node >= N_NODES) return;
  int2 ri = rowinfo[node];
  const uint32* ep = edges + ri.x;
  int n = ri.y;
  float s = bf2f(sio[((size_t)node << 5) + c]);  // hoisted
  float a0 = 0.f, a1 = 0.f, a2 = 0.f, a3 = 0.f;
  for (int e = 0; e < n; e += 16) {
    int el = e + (c & 15);
    uint32 me = ep[el < n ? el : n - 1];   // ONE coalesced load: 16 edge words
    uint32 d[16];
#pragma unroll
    for (int j = 0; j < 16; j++) d[j] = __shfl(me, j, 32);
    int g[16];
#pragma unroll
    for (int j = 0; j < 16; j++) {
      g[j] = (int)tin[((size_t)(d[j] >> 14) << 5) + c];   // 16 gathers in flight
    }
#pragma unroll
    for (int j = 0; j < 16; j++) {
      float v = (e + j < n) ? (float)(d[j] & 0x3FFFu) : 0.f;
      if ((j & 3) == 0) a0 = fmaf(v, (float)g[j], a0);
      else if ((j & 3) == 1) a1 = fmaf(v, (float)g[j], a1);
      else if ((j & 3) == 2) a2 = fmaf(v, (float)g[j], a2);
      else a3 = fmaf(v, (float)g[j], a3);
    }
  }
  float acc = ((a0 + a1) + (a2 + a3)) * (1.f / (16383.f * TSCALE));
  float h = fmaxf(acc + s + bias[c], 0.f);
  if (MODE == 1) {
    hout[((size_t)node << 5) + c] = h;
  } else {
    float m1 = 0.f, m2 = 0.f;
#pragma unroll
    for (int k = 0; k < CH; k++) {
      float hk = __shfl(h, k, 32);
      m1 = fmaf(hk, W1n[k * CH + c], m1);
      m2 = fmaf(hk, W2n[k * CH + c], m2);
    }
    tout[((size_t)node << 5) + c] = f2q8(m1);   // 64 consecutive bytes per wave
    sio[((size_t)node << 5) + c] = f2bf(m2);    // in-place: read happened above
  }
}

// =======================================================================
// pool (segment mean via binary search) + dense + softmax
// =======================================================================

__global__ void k_head(const float* __restrict__ h, const int* __restrict__ seg,
                       const float* __restrict__ Wd, const float* __restrict__ bd,
                       float* __restrict__ out) {
  int g = blockIdx.x;
  int t = threadIdx.x;
  __shared__ float red[64];
  __shared__ float pooled[CH];
  __shared__ float logits[N_LABELS];
  int lo, hi;
  {
    int l = 0, r = N_NODES;
    while (l < r) { int m = (l + r) >> 1; if (seg[m] < g) l = m + 1; else r = m; }
    lo = l;
  }
  {
    int l = 0, r = N_NODES;
    while (l < r) { int m = (l + r) >> 1; if (seg[m] < g + 1) l = m + 1; else r = m; }
    hi = l;
  }
  float acc = 0.f;
  int c = t & 31, half = t >> 5;
  for (int i = lo + half; i < hi; i += 2) acc += h[(size_t)i * CH + c];
  red[t] = acc;
  __syncthreads();
  if (t < CH) {
    float cnt = (float)((hi - lo) > 0 ? (hi - lo) : 1);
    pooled[t] = (red[t] + red[t + 32]) / cnt;
  }
  __syncthreads();
  if (t < N_LABELS) {
    float a = bd[t];
#pragma unroll
    for (int k = 0; k < CH; k++) a = fmaf(pooled[k], Wd[k * N_LABELS + t], a);
    logits[t] = a;
  }
  __syncthreads();
  if (t == 0) {
    float mx = logits[0];
    for (int j = 1; j < N_LABELS; j++) mx = fmaxf(mx, logits[j]);
    float ssum = 0.f;
    float e[N_LABELS];
    for (int j = 0; j < N_LABELS; j++) { e[j] = expf(logits[j] - mx); ssum += e[j]; }
    float inv = 1.f / ssum;
    for (int j = 0; j < N_LABELS; j++) out[(size_t)g * N_LABELS + j] = e[j] * inv;
  }
}

// =======================================================================
// launch
// =======================================================================

extern "C" void kernel_launch(void* const* d_in, const int* in_sizes, int n_in,
                              void* d_out, int out_size, void* d_ws, size_t ws_size,
                              hipStream_t stream) {
  const float* x    = (const float*)d_in[0];
  const int*   arow = (const int*)d_in[1];
  const int*   acol = (const int*)d_in[2];
  const float* aval = (const float*)d_in[3];
  const int*   seg  = (const int*)d_in[4];
  const float* W1_1 = (const float*)d_in[5];
  const float* W2_1 = (const float*)d_in[6];
  const float* b_1  = (const float*)d_in[7];
  const float* W1_2 = (const float*)d_in[8];
  const float* W2_2 = (const float*)d_in[9];
  const float* b_2  = (const float*)d_in[10];
  const float* W1_3 = (const float*)d_in[11];
  const float* W2_3 = (const float*)d_in[12];
  const float* b_3  = (const float*)d_in[13];
  const float* Wd   = (const float*)d_in[14];
  const float* bd   = (const float*)d_in[15];
  float* out = (float*)d_out;

  char* w = (char*)d_ws;
  signed char* tA = (signed char*)w; w += (size_t)N_NODES * CH;      // 6.4 MB
  signed char* tB = (signed char*)w; w += (size_t)N_NODES * CH;      // 6.4 MB
  u16* sS = (u16*)w;                 w += (size_t)N_NODES * CH * 2;  // 12.8 MB
  float* hbuf = (float*)w;           w += (size_t)N_NODES * CH * 4;  // 25.6 MB
  uint32* edges = (uint32*)w;        w += (size_t)NBUCK * CAP * 4;   // 16.0 MB
  int2* rowinfo = (int2*)w;          w += (size_t)N_NODES * 8;       // 1.6 MB
  int* bucketCur = (int*)w;          w += 4096;
  uint32* xT = (uint32*)w;           w += (size_t)64 * N_NODES * 4;  // 51.2 MB
  // records (32 MB) aliases [tA|tB|sS|hbuf] (51.2 MB): dead after passB,
  // before k_dense1 writes tA/sS. xT is a separate region (as in r10).
  unsigned long long* records = (unsigned long long*)d_ws;

  // ---- build exact compact CSR ----
  hipMemsetAsync(bucketCur, 0, (size_t)NBUCK * 4, stream);
  k_passA<<<(N_EDGES + EPB - 1) / EPB, 256, 0, stream>>>(arow, acol, aval, bucketCur, records);
  k_passB<<<NBUCK, 512, 0, stream>>>(bucketCur, records, rowinfo, edges);

  // ---- transpose x (fp32 [node][k] -> bf16-pair [k/2][node]) ----
  k_xpose<<<(N_NODES + 255) / 256, 256, 0, stream>>>(x, xT);

  // ---- layer 1 dense projections (project BEFORE aggregation: 128 -> 32) ----
  k_dense1<<<(N_NODES + 255) / 256, 256, 0, stream>>>(xT, W1_1, W2_1, tA, sS);

  const int GCS_GRID = (N_NODES * 32 + 255) / 256;
  // layer 1 (+ layer-2 dense), layer 2 (+ layer-3 dense), layer 3 (combine only)
  k_gcs<0><<<GCS_GRID, 256, 0, stream>>>(rowinfo, edges, tA, sS, b_1, W1_2, W2_2, tB, nullptr);
  k_gcs<0><<<GCS_GRID, 256, 0, stream>>>(rowinfo, edges, tB, sS, b_2, W1_3, W2_3, tA, nullptr);
  k_gcs<1><<<GCS_GRID, 256, 0, stream>>>(rowinfo, edges, tA, sS, b_3, nullptr, nullptr, nullptr, hbuf);

  // ---- pool + head + softmax ----
  k_head<<<N_GRAPHS, 64, 0, stream>>>(hbuf, seg, Wd, bd, out);
}

// Round 18
// 409.319 us; speedup vs baseline: 1.1316x; 1.1316x over previous
//
#include <hip/hip_runtime.h>
#include <cstdint>

#define N_NODES 200000
#define N_EDGES 3200000
#define F_IN 128
#define CH 32
#define N_GRAPHS 1024
#define N_LABELS 17

#define BROWS 512                 // rows per bucket
#define NBUCK ((N_NODES + BROWS - 1) / BROWS)   // 391
#define CAP 10240                 // record capacity per bucket (mean 8192, sd ~90)
#define EPB 8192                  // edges per workgroup in pass A

typedef unsigned int uint32;
typedef unsigned short u16;

#define TSCALE 16.f               // int8 t-table fixed-point scale (abs err 1/32)

__device__ __forceinline__ u16 f2bf(float f) {
  unsigned int u = __float_as_uint(f);
  u = (u + 0x7FFFu + ((u >> 16) & 1u)) >> 16;  // round-to-nearest-even
  return (u16)u;
}
__device__ __forceinline__ float bf2f(u16 h) {
  return __uint_as_float(((unsigned int)h) << 16);
}
__device__ __forceinline__ signed char f2q8(float f) {
  float qf = fmaxf(-127.f, fminf(127.f, rintf(f * TSCALE)));
  return (signed char)(int)qf;
}

// =======================================================================
// Pass A: bucket edges into per-bucket record regions (packed 8B records)
// record = ((rl<<18 | col) << 32) | float_bits(val)
// =======================================================================

__global__ __launch_bounds__(256) void k_passA(const int* __restrict__ arow,
                                               const int* __restrict__ acol,
                                               const float* __restrict__ aval,
                                               int* __restrict__ bucketCur,
                                               unsigned long long* __restrict__ records) {
  __shared__ int cnt[NBUCK];
  __shared__ int base[NBUCK];
  int t = threadIdx.x;
  for (int i = t; i < NBUCK; i += 256) cnt[i] = 0;
  __syncthreads();
  int e0 = blockIdx.x * EPB;
  int e1 = e0 + EPB; if (e1 > N_EDGES) e1 = N_EDGES;
  for (int e = e0 + t; e < e1; e += 256) atomicAdd(&cnt[arow[e] >> 9], 1);
  __syncthreads();
  for (int i = t; i < NBUCK; i += 256) {
    int n = cnt[i];
    base[i] = n ? atomicAdd(&bucketCur[i], n) : 0;
    cnt[i] = 0;  // reuse as local cursor
  }
  __syncthreads();
  for (int e = e0 + t; e < e1; e += 256) {
    int r = arow[e];
    int b = r >> 9;
    int p = atomicAdd(&cnt[b], 1) + base[b];
    if (p < CAP) {
      unsigned int hi = ((unsigned int)(r & 511) << 18) | (unsigned int)acol[e];
      unsigned long long rec = ((unsigned long long)hi << 32) |
                               (unsigned int)__float_as_int(aval[e]);
      records[(size_t)b * CAP + p] = rec;
    }
  }
}

// =======================================================================
// Pass B: one WG per bucket -> exact compact CSR
// edge record: 4 bytes = (col:18 << 14) | q14(val); val = q * (1/16383)
// =======================================================================

__global__ __launch_bounds__(512) void k_passB(const int* __restrict__ bucketCur,
                                               const unsigned long long* __restrict__ records,
                                               int2* __restrict__ rowinfo,
                                               uint32* __restrict__ edges) {
  __shared__ int cnt[BROWS];
  __shared__ int sc[BROWS];
  __shared__ int cur[BROWS];
  int b = blockIdx.x;
  int t = threadIdx.x;
  int nrec = bucketCur[b]; if (nrec > CAP) nrec = CAP;
  const unsigned long long* rp = records + (size_t)b * CAP;
  cnt[t] = 0;
  __syncthreads();
  for (int i = t; i < nrec; i += 512) {
    unsigned int hi = (unsigned int)(rp[i] >> 32);
    atomicAdd(&cnt[hi >> 18], 1);
  }
  __syncthreads();
  sc[t] = cnt[t];
  __syncthreads();
  for (int d = 1; d < BROWS; d <<= 1) {
    int v = (t >= d) ? sc[t - d] : 0;
    __syncthreads();
    sc[t] += v;
    __syncthreads();
  }
  int pre = sc[t] - cnt[t];  // exclusive prefix
  cur[t] = pre;
  int r = b * BROWS + t;
  if (r < N_NODES) rowinfo[r] = make_int2(b * CAP + pre, cnt[t]);
  __syncthreads();
  for (int i = t; i < nrec; i += 512) {
    unsigned long long rec = rp[i];
    unsigned int hi = (unsigned int)(rec >> 32);
    int rl = hi >> 18;
    unsigned int col = hi & 0x3FFFFu;
    float val = __int_as_float((int)(unsigned int)rec);
    int q = (int)fmaf(val, 16383.f, 0.5f);
    q = q < 0 ? 0 : (q > 16383 ? 16383 : q);
    int p = atomicAdd(&cur[rl], 1);
    edges[(size_t)b * CAP + p] = (col << 14) | (unsigned int)q;
  }
}

// =======================================================================
// dense layer 1: t = x@W1 (int8 out), s = x@W2 (bf16 out)
// r9-proven form: thread-per-node, SGPR-uniform weight path, compiler-
// scheduled. Seven restructurings (LDS stage, lane-split, block-split,
// transpose x2, ping-pong, asm fence) ALL lost to this — it stays.
// =======================================================================

__global__ __launch_bounds__(256) void k_dense1(const float* __restrict__ x,
                                                const float* __restrict__ W1,
                                                const float* __restrict__ W2,
                                                signed char* __restrict__ tout,
                                                u16* __restrict__ sout) {
  int i = blockIdx.x * blockDim.x + threadIdx.x;
  if (i >= N_NODES) return;
  const float* xr = x + (size_t)i * F_IN;
  float acc1[CH], acc2[CH];
#pragma unroll
  for (int c = 0; c < CH; c++) { acc1[c] = 0.f; acc2[c] = 0.f; }
#pragma unroll 8
  for (int k = 0; k < F_IN; k += 4) {
    float4 xv = *(const float4*)(xr + k);
    float xk[4] = {xv.x, xv.y, xv.z, xv.w};
#pragma unroll
    for (int kk = 0; kk < 4; kk++) {
      float xval = xk[kk];
      const float* w1r = W1 + (size_t)(k + kk) * CH;
      const float* w2r = W2 + (size_t)(k + kk) * CH;
#pragma unroll
      for (int c = 0; c < CH; c++) {
        acc1[c] = fmaf(xval, w1r[c], acc1[c]);
        acc2[c] = fmaf(xval, w2r[c], acc2[c]);
      }
    }
  }
  uint32* tp = (uint32*)(tout + (size_t)i * CH);
#pragma unroll
  for (int c = 0; c < CH; c += 4) {
    uint32 p = ((uint32)(unsigned char)f2q8(acc1[c])) |
               ((uint32)(unsigned char)f2q8(acc1[c + 1]) << 8) |
               ((uint32)(unsigned char)f2q8(acc1[c + 2]) << 16) |
               ((uint32)(unsigned char)f2q8(acc1[c + 3]) << 24);
    tp[c >> 2] = p;
  }
  uint32* sp = (uint32*)(sout + (size_t)i * CH);
#pragma unroll
  for (int c = 0; c < CH; c += 2) {
    sp[c >> 1] = (uint32)f2bf(acc2[c]) | ((uint32)f2bf(acc2[c + 1]) << 16);
  }
}

// =======================================================================
// Fused: agg = SpMM(t_int8) ; h = relu(agg + s + b) ; [t',s'] = h @ [W1n,W2n]
// Edge words: one coalesced load per 16 + in-register shfl broadcast.
// INT dot product: q14 x int8 via __mul24 mad (v_mad_i32_i24, 1 VALU op)
// replaces 2x v_cvt + v_fma per edge — exact integer accumulation
// (max |acc| = 13 edges x 2.08M << 2^31), one cvt per node at the end.
// =======================================================================

template <int MODE>
__global__ __launch_bounds__(256) void k_gcs(const int2* __restrict__ rowinfo,
                                             const uint32* __restrict__ edges,
                                             const signed char* __restrict__ tin,
                                             u16* __restrict__ sio,
                                             const float* __restrict__ bias,
                                             const float* __restrict__ W1n,
                                             const float* __restrict__ W2n,
                                             signed char* __restrict__ tout,
                                             float* __restrict__ hout) {
  int gid = blockIdx.x * blockDim.x + threadIdx.x;
  int node = gid >> 5;
  int c = gid & 31;
  if (node >= N_NODES) return;
  int2 ri = rowinfo[node];
  const uint32* ep = edges + ri.x;
  int n = ri.y;
  float s = bf2f(sio[((size_t)node << 5) + c]);  // hoisted
  int a0 = 0, a1 = 0, a2 = 0, a3 = 0;
  for (int e = 0; e < n; e += 16) {
    int el = e + (c & 15);
    uint32 me = ep[el < n ? el : n - 1];   // ONE coalesced load: 16 edge words
    uint32 d[16];
#pragma unroll
    for (int j = 0; j < 16; j++) d[j] = __shfl(me, j, 32);
    int g[16];
#pragma unroll
    for (int j = 0; j < 16; j++) {
      g[j] = (int)tin[((size_t)(d[j] >> 14) << 5) + c];   // 16 gathers in flight
    }
#pragma unroll
    for (int j = 0; j < 16; j++) {
      int v = (e + j < n) ? (int)(d[j] & 0x3FFFu) : 0;
      if ((j & 3) == 0) a0 += __mul24(v, g[j]);
      else if ((j & 3) == 1) a1 += __mul24(v, g[j]);
      else if ((j & 3) == 2) a2 += __mul24(v, g[j]);
      else a3 += __mul24(v, g[j]);
    }
  }
  float acc = (float)((a0 + a1) + (a2 + a3)) * (1.f / (16383.f * TSCALE));
  float h = fmaxf(acc + s + bias[c], 0.f);
  if (MODE == 1) {
    hout[((size_t)node << 5) + c] = h;
  } else {
    float m1 = 0.f, m2 = 0.f;
#pragma unroll
    for (int k = 0; k < CH; k++) {
      float hk = __shfl(h, k, 32);
      m1 = fmaf(hk, W1n[k * CH + c], m1);
      m2 = fmaf(hk, W2n[k * CH + c], m2);
    }
    tout[((size_t)node << 5) + c] = f2q8(m1);   // 64 consecutive bytes per wave
    sio[((size_t)node << 5) + c] = f2bf(m2);    // in-place: read happened above
  }
}

// =======================================================================
// pool (segment mean via binary search) + dense + softmax
// =======================================================================

__global__ void k_head(const float* __restrict__ h, const int* __restrict__ seg,
                       const float* __restrict__ Wd, const float* __restrict__ bd,
                       float* __restrict__ out) {
  int g = blockIdx.x;
  int t = threadIdx.x;
  __shared__ float red[64];
  __shared__ float pooled[CH];
  __shared__ float logits[N_LABELS];
  int lo, hi;
  {
    int l = 0, r = N_NODES;
    while (l < r) { int m = (l + r) >> 1; if (seg[m] < g) l = m + 1; else r = m; }
    lo = l;
  }
  {
    int l = 0, r = N_NODES;
    while (l < r) { int m = (l + r) >> 1; if (seg[m] < g + 1) l = m + 1; else r = m; }
    hi = l;
  }
  float acc = 0.f;
  int c = t & 31, half = t >> 5;
  for (int i = lo + half; i < hi; i += 2) acc += h[(size_t)i * CH + c];
  red[t] = acc;
  __syncthreads();
  if (t < CH) {
    float cnt = (float)((hi - lo) > 0 ? (hi - lo) : 1);
    pooled[t] = (red[t] + red[t + 32]) / cnt;
  }
  __syncthreads();
  if (t < N_LABELS) {
    float a = bd[t];
#pragma unroll
    for (int k = 0; k < CH; k++) a = fmaf(pooled[k], Wd[k * N_LABELS + t], a);
    logits[t] = a;
  }
  __syncthreads();
  if (t == 0) {
    float mx = logits[0];
    for (int j = 1; j < N_LABELS; j++) mx = fmaxf(mx, logits[j]);
    float ssum = 0.f;
    float e[N_LABELS];
    for (int j = 0; j < N_LABELS; j++) { e[j] = expf(logits[j] - mx); ssum += e[j]; }
    float inv = 1.f / ssum;
    for (int j = 0; j < N_LABELS; j++) out[(size_t)g * N_LABELS + j] = e[j] * inv;
  }
}

// =======================================================================
// launch
// =======================================================================

extern "C" void kernel_launch(void* const* d_in, const int* in_sizes, int n_in,
                              void* d_out, int out_size, void* d_ws, size_t ws_size,
                              hipStream_t stream) {
  const float* x    = (const float*)d_in[0];
  const int*   arow = (const int*)d_in[1];
  const int*   acol = (const int*)d_in[2];
  const float* aval = (const float*)d_in[3];
  const int*   seg  = (const int*)d_in[4];
  const float* W1_1 = (const float*)d_in[5];
  const float* W2_1 = (const float*)d_in[6];
  const float* b_1  = (const float*)d_in[7];
  const float* W1_2 = (const float*)d_in[8];
  const float* W2_2 = (const float*)d_in[9];
  const float* b_2  = (const float*)d_in[10];
  const float* W1_3 = (const float*)d_in[11];
  const float* W2_3 = (const float*)d_in[12];
  const float* b_3  = (const float*)d_in[13];
  const float* Wd   = (const float*)d_in[14];
  const float* bd   = (const float*)d_in[15];
  float* out = (float*)d_out;

  char* w = (char*)d_ws;
  signed char* tA = (signed char*)w; w += (size_t)N_NODES * CH;      // 6.4 MB
  signed char* tB = (signed char*)w; w += (size_t)N_NODES * CH;      // 6.4 MB
  u16* sS = (u16*)w;                 w += (size_t)N_NODES * CH * 2;  // 12.8 MB
  float* hbuf = (float*)w;           w += (size_t)N_NODES * CH * 4;  // 25.6 MB
  uint32* edges = (uint32*)w;        w += (size_t)NBUCK * CAP * 4;   // 16.0 MB
  int2* rowinfo = (int2*)w;          w += (size_t)N_NODES * 8;       // 1.6 MB
  int* bucketCur = (int*)w;          w += 4096;
  // records (32 MB) aliases [tA|tB|sS|hbuf] (51.2 MB): dead before k_dense1
  unsigned long long* records = (unsigned long long*)d_ws;

  // ---- build exact compact CSR ----
  hipMemsetAsync(bucketCur, 0, (size_t)NBUCK * 4, stream);
  k_passA<<<(N_EDGES + EPB - 1) / EPB, 256, 0, stream>>>(arow, acol, aval, bucketCur, records);
  k_passB<<<NBUCK, 512, 0, stream>>>(bucketCur, records, rowinfo, edges);

  // ---- layer 1 dense projections (project BEFORE aggregation: 128 -> 32) ----
  k_dense1<<<(N_NODES + 255) / 256, 256, 0, stream>>>(x, W1_1, W2_1, tA, sS);

  const int GCS_GRID = (N_NODES * 32 + 255) / 256;
  // layer 1 (+ layer-2 dense), layer 2 (+ layer-3 dense), layer 3 (combine only)
  k_gcs<0><<<GCS_GRID, 256, 0, stream>>>(rowinfo, edges, tA, sS, b_1, W1_2, W2_2, tB, nullptr);
  k_gcs<0><<<GCS_GRID, 256, 0, stream>>>(rowinfo, edges, tB, sS, b_2, W1_3, W2_3, tA, nullptr);
  k_gcs<1><<<GCS_GRID, 256, 0, stream>>>(rowinfo, edges, tA, sS, b_3, nullptr, nullptr, nullptr, hbuf);

  // ---- pool + head + softmax ----
  k_head<<<N_GRAPHS, 64, 0, stream>>>(hbuf, seg, Wd, bd, out);
}